// Round 12
// baseline (429.271 us; speedup 1.0000x reference)
//
#include <hip/hip_runtime.h>

#define EMB   256
#define HID   128
#define RELD  64
#define NREL  10
#define TE    128
#define SHSTR 130   // sHid k-group stride in 16B units (+2 pad: keeps the u16
                    // epilogue/attend writes conflict-free — R10: 18M -> 0)

typedef __attribute__((ext_vector_type(8)))  short bf16x8;
typedef __attribute__((ext_vector_type(16))) float f32x16;

__device__ __forceinline__ float bf16_to_f32(unsigned short u) {
    union { unsigned int i; float f; } v;
    v.i = ((unsigned int)u) << 16;
    return v.f;
}

__device__ __forceinline__ unsigned short f32_to_bf16(float x) {
    union { unsigned int i; float f; } v;
    v.f = x;
    unsigned int b = v.i;
    unsigned int rounded = b + 0x7fffu + ((b >> 16) & 1u);   // round-nearest-even
    return (unsigned short)(rounded >> 16);
}

template <bool F32>
__device__ __forceinline__ float ldx(const void* p, size_t i) {
    if (F32) return ((const float*)p)[i];
    return bf16_to_f32(((const unsigned short*)p)[i]);
}

// In-kernel parallel dtype detect (validated rounds 7-12: fp32 inputs -> true).
__device__ __forceinline__ bool detect_f32(const void* nodeEmb) {
    const float* f = (const float*)nodeEmb;
    float x = f[(threadIdx.x & 63) * 997];
    bool sane = isfinite(x) && fabsf(x) < 1.0e6f;
    unsigned long long m = __ballot(sane);
    return __popcll(m) >= 48;
}

// Register-free async global->LDS (16B per lane). LDS dest must be the
// wave-uniform base; HW adds lane*16.
__device__ __forceinline__ void gload16(const void* g, void* l) {
    __builtin_amdgcn_global_load_lds(
        (const __attribute__((address_space(1))) unsigned int*)g,
        (__attribute__((address_space(3))) unsigned int*)l, 16, 0, 0);
}

// ---- T4 counted-vmcnt barrier kit -----------------------------------------
#define WAITVL(n) asm volatile("s_waitcnt vmcnt(" #n ") lgkmcnt(0)" ::: "memory")

__device__ __forceinline__ void sbar() {           // raw workgroup barrier,
    __builtin_amdgcn_sched_barrier(0);             // no vmcnt drain
    __builtin_amdgcn_s_barrier();
    __builtin_amdgcn_sched_barrier(0);
}
__device__ __forceinline__ void bar_lds() {        // phase barrier: LDS-visible,
    asm volatile("s_waitcnt lgkmcnt(0)" ::: "memory");  // vmem prefetches survive
    sbar();
}

// ---------------------------------------------------------------------------
// Merged prep kernel (conversion kept — R8 A/B: bf16 table saves ~124 us on
// main for ~37 us of prep):
//   blocks [0, convBlocks)    : fp32 node table -> bf16 copy
//   blocks [convBlocks, +448) : weights -> bf16 in MFMA-FRAGMENT ORDER
//   block  convBlocks+448     : per-relation Q table (10x128 fp32)
// ---------------------------------------------------------------------------
template <bool F32>
__device__ void prep_body(int vb, const void* W_edge, const void* W_k,
                          const void* W_v, const void* W_o1, const void* rel_emb,
                          const void* W_q, const void* b_q,
                          unsigned short* WTe, unsigned short* WTk,
                          unsigned short* WTv, unsigned short* WTo1, float* Qtab)
{
    if (vb < 448) {
        int idx = vb * 256 + threadIdx.x;             // 0 .. 114687
        if (idx < 65536) {                            // W_edge: 16 chunks x 4096
            int kc = idx >> 12, e = idx & 4095;
            int g = e >> 3, j = e & 7;
            int col = g & 127, kg = g >> 7;
            int k = kc * 32 + kg * 8 + j;
            WTe[idx] = f32_to_bf16(ldx<F32>(W_edge, (size_t)k * HID + col));
        } else if (idx < 65536 + 16384) {             // W_k: 4 chunks x 4096
            int i = idx - 65536;
            int kc = i >> 12, e = i & 4095;
            int g = e >> 3, j = e & 7;
            int col = g & 127, kg = (g >> 7) & 3;
            int k = kc * 32 + kg * 8 + j;
            WTk[i] = f32_to_bf16(ldx<F32>(W_k, (size_t)k * HID + col));
        } else if (idx < 65536 + 2 * 16384) {
            int i = idx - 65536 - 16384;
            int kc = i >> 12, e = i & 4095;
            int g = e >> 3, j = e & 7;
            int col = g & 127, kg = (g >> 7) & 3;
            int k = kc * 32 + kg * 8 + j;
            WTv[i] = f32_to_bf16(ldx<F32>(W_v, (size_t)k * HID + col));
        } else {
            int i = idx - 65536 - 2 * 16384;
            int kc = i >> 12, e = i & 4095;
            int g = e >> 3, j = e & 7;
            int col = g & 127, kg = (g >> 7) & 3;
            int k = kc * 32 + kg * 8 + j;
            WTo1[i] = f32_to_bf16(ldx<F32>(W_o1, (size_t)k * HID + col));
        }
    } else {
        const int t = threadIdx.x;
        const int c = t & (HID - 1);
        const int h = t >> 7;
        for (int r = h; r < NREL; r += 2) {
            float acc = 0.f;
            for (int d = 0; d < RELD; ++d)
                acc += ldx<F32>(rel_emb, r * RELD + d) * ldx<F32>(W_q, (size_t)d * HID + c);
            Qtab[r * HID + c] = acc + ldx<F32>(b_q, c);
        }
    }
}

__global__ void prep_kernel(const void* nodeEmb,
                            const void* W_edge, const void* W_k, const void* W_v,
                            const void* W_o1, const void* rel_emb, const void* W_q,
                            const void* b_q,
                            unsigned short* WTe, unsigned short* WTk,
                            unsigned short* WTv, unsigned short* WTo1, float* Qtab,
                            unsigned short* nodeBf16, int convBlocks,
                            unsigned long long nodeElems)
{
    bool f32 = detect_f32(nodeEmb);
    int b = blockIdx.x;
    if (b < convBlocks) {
        if (!f32) return;                             // bf16 input: no conversion
        unsigned long long i = (unsigned long long)b * 2048ull + threadIdx.x * 8;
        if (i + 8 <= nodeElems) {
            const float* src = (const float*)nodeEmb + i;
            float4 f0 = *(const float4*)src;
            float4 f1 = *(const float4*)(src + 4);
            union { unsigned short us[8]; uint4 v; } pk;
            pk.us[0] = f32_to_bf16(f0.x); pk.us[1] = f32_to_bf16(f0.y);
            pk.us[2] = f32_to_bf16(f0.z); pk.us[3] = f32_to_bf16(f0.w);
            pk.us[4] = f32_to_bf16(f1.x); pk.us[5] = f32_to_bf16(f1.y);
            pk.us[6] = f32_to_bf16(f1.z); pk.us[7] = f32_to_bf16(f1.w);
            *(uint4*)(nodeBf16 + i) = pk.v;
        }
        return;
    }
    b -= convBlocks;
    if (f32) prep_body<true >(b, W_edge, W_k, W_v, W_o1, rel_emb, W_q, b_q,
                              WTe, WTk, WTv, WTo1, Qtab);
    else     prep_body<false>(b, W_edge, W_k, W_v, W_o1, rel_emb, W_q, b_q,
                              WTe, WTk, WTv, WTo1, Qtab);
}

// ---------------------------------------------------------------------------
// Shared memory, 80384 B -> 2 blocks/CU. R11: SB holds a BK=64 chunk
// (two consecutive 32-k sub-chunks of the unchanged WT layout, 16 KB),
// double-buffered. sHid in padded fragment order (R10, conflict-free).
// ---------------------------------------------------------------------------
struct __align__(16) Smem {
    unsigned short sHid[16 * SHSTR * 8]; // 33280 B
    unsigned short SB[2][8192];          // 32768 B: double-buffered BK=64 chunk
    float sQf[NREL * HID];               // 5120 B
    float sBias[5 * HID];                // 2560 B: b_edge|b_k|b_v|b_o1|W_o2
    float sSc[TE][4];                    // 2048 B
    float sAttn[TE][4];                  // 2048 B
    float sPart[TE][2];                  // 1024 B
    int   sSrc[TE], sTgt[TE], sRel[TE];  // 1536 B
};                                       // total 80384 B

// sHid element address (row, k) -> short index
__device__ __forceinline__ int shid_idx(int row, int k) {
    return (((k >> 3) * SHSTR + row) << 3) + (k & 7);
}

// A-fragment load straight from a node row (bf16 table or fp32 fallback).
template <bool GBF16>
__device__ __forceinline__ bf16x8 loadA8(const void* row, int off) {
    if (GBF16) {
        return *(const bf16x8*)((const unsigned short*)row + off);
    } else {
        const float* p = (const float*)row + off;
        float4 f0 = *(const float4*)p;
        float4 f1 = *(const float4*)(p + 4);
        union { unsigned short us[8]; bf16x8 v; } pk;
        pk.us[0] = f32_to_bf16(f0.x); pk.us[1] = f32_to_bf16(f0.y);
        pk.us[2] = f32_to_bf16(f0.z); pk.us[3] = f32_to_bf16(f0.w);
        pk.us[4] = f32_to_bf16(f1.x); pk.us[5] = f32_to_bf16(f1.y);
        pk.us[6] = f32_to_bf16(f1.z); pk.us[7] = f32_to_bf16(f1.w);
        return pk.v;
    }
}

// ---------------------------------------------------------------------------
// Fused pipeline, 32x32x16 MFMA. Block = 128 edges, 512 threads = 8 waves.
// Wave w: rt=w>>1 (rows 32rt..+31), cg2=w&1 (cols 64cg2..+63).
//
// R11: BK=64 — iteration-slot count halved (28 -> 14). R10's counter math
// showed time = slots x ~1.46k-cycle fixed slot cost (MfmaUtil 18.8% ==
// 256cy MFMA content / 1460); doubling content per slot attacks the fixed
// part. A: rolling aR[2][4] regs, distance-2 issue (~2-slot cover).
// B: LDS double-buffer, counted vmcnt (never 0 mid-loop).
// WAITVL literals derived for the bf16 issue stream (6 vmem/iter). The fp32
// fallback path (GBF16=false, workspace-starved only) uses WAITVL(0):
// compiler-drained A-loads would make counted waits under-wait (desk-check
// R11.5) — conservative drain is correct there.
// ---------------------------------------------------------------------------
template <bool F32, bool GBF16>
__device__ void fused_body(
    Smem& sm,
    const void* gsrc, const int* edgeIdx, const int* relType,
    const unsigned short* WTe, const unsigned short* WTk,
    const unsigned short* WTv, const unsigned short* WTo1,
    const void* b_edge, const void* b_k, const void* b_v,
    const void* b_o1, const void* W_o2, const void* b_o2,
    const float* Qtab, void* outp, int E)
{
    const int t   = threadIdx.x;
    const int l   = t & 63;
    const int w   = t >> 6;          // 0..7
    const int c   = l & 31;
    const int h5  = l >> 5;
    const int rt  = w >> 1;          // 0..3  row tile
    const int cg2 = w & 1;           // 0..1  col tile
    const int bs  = blockIdx.x * TE;
    const int aRow = 32 * rt + c;

    // ---- preamble ----
    if (t < TE) {
        int e = bs + t;
        if (e >= E) e = E - 1;
        if (e < 0)  e = 0;
        sm.sSrc[t] = edgeIdx[e];
        sm.sTgt[t] = edgeIdx[E + e];
        int r = relType[e];
        if (r < 0) r = 0;
        if (r >= NREL) r = NREL - 1;
        sm.sRel[t] = r;
    }
    for (int i = t; i < 5 * HID; i += 512) {
        int which = i >> 7, j = i & (HID - 1);
        float v = (which == 0) ? ldx<F32>(b_edge, j)
                : (which == 1) ? ldx<F32>(b_k, j)
                : (which == 2) ? ldx<F32>(b_v, j)
                : (which == 3) ? ldx<F32>(b_o1, j)
                               : ldx<F32>(W_o2, j);
        sm.sBias[i] = v;
    }
    for (int i = t; i < NREL * HID; i += 512)
        sm.sQf[i] = Qtab[i];
    __syncthreads();

    // Per-lane node-row pointers for this lane's A-row (GEMM1 direct loads).
    const void* rowSrc;
    const void* rowTgt;
    if (GBF16) {
        rowSrc = (const void*)((const unsigned short*)gsrc + (size_t)sm.sSrc[aRow] * EMB);
        rowTgt = (const void*)((const unsigned short*)gsrc + (size_t)sm.sTgt[aRow] * EMB);
    } else {
        rowSrc = (const void*)((const float*)gsrc + (size_t)sm.sSrc[aRow] * EMB);
        rowTgt = (const void*)((const float*)gsrc + (size_t)sm.sTgt[aRow] * EMB);
    }

    char* const ldsB0 = (char*)sm.SB[0] + w * 1024;   // wave slice, sub-chunk 0
    char* const ldsB1 = (char*)sm.SB[1] + w * 1024;

    // LOAD_A: 32-k sub-chunk k32, half s (16 B = one A fragment)
    #define LOAD_A(k32, s) \
        loadA8<GBF16>(((k32) < 8) ? rowSrc : rowTgt, ((k32) & 7) * 32 + (s) * 16 + h5 * 8)
    // STAGE_B64: BK=64 chunk kc of table WT -> SB[buf] (2 gload16/thread)
    #define STAGE_B64(WT, kc, buf)                                               \
    {                                                                            \
        gload16((WT) + (2 * (kc)    ) * 4096 + t * 8,                            \
                ((buf) ? ldsB1 : ldsB0));                                        \
        gload16((WT) + (2 * (kc) + 1) * 4096 + t * 8,                            \
                ((buf) ? ldsB1 : ldsB0) + 8192);                                 \
    }

    // MFMA on one BK=64 chunk, A from aR[slot][h*2+s], B from SB[buf]
    #define MFMA_AR64(slot, buf, accv)                                           \
    {                                                                            \
        const char* sb_ = (const char*)sm.SB[(buf)];                             \
        _Pragma("unroll")                                                        \
        for (int h_ = 0; h_ < 2; ++h_)                                           \
        _Pragma("unroll")                                                        \
        for (int s_ = 0; s_ < 2; ++s_) {                                         \
            _Pragma("unroll")                                                    \
            for (int ct_ = 0; ct_ < 2; ++ct_) {                                  \
                bf16x8 b_ = *(const bf16x8*)                                     \
                    (sb_ + h_ * 8192 +                                           \
                     ((s_ * 256 + h5 * 128 + 64 * cg2 + 32 * ct_ + c) << 4));    \
                accv[ct_] = __builtin_amdgcn_mfma_f32_32x32x16_bf16(             \
                                aR[slot][h_ * 2 + s_], b_, accv[ct_], 0, 0, 0);  \
            }                                                                    \
        }                                                                        \
    }

    // MFMA on one BK=64 chunk, A from sHid (k32 = 2*kc+h), B from SB[buf]
    #define MFMA_H64(kc, buf, accv)                                              \
    {                                                                            \
        const char* sb_ = (const char*)sm.SB[(buf)];                             \
        _Pragma("unroll")                                                        \
        for (int h_ = 0; h_ < 2; ++h_)                                           \
        _Pragma("unroll")                                                        \
        for (int s_ = 0; s_ < 2; ++s_) {                                         \
            bf16x8 a_ = *(const bf16x8*)((const char*)sm.sHid +                  \
                ((((2 * (kc) + h_) * 4 + s_ * 2 + h5) * SHSTR + aRow) << 4));    \
            _Pragma("unroll")                                                    \
            for (int ct_ = 0; ct_ < 2; ++ct_) {                                  \
                bf16x8 b_ = *(const bf16x8*)                                     \
                    (sb_ + h_ * 8192 +                                           \
                     ((s_ * 256 + h5 * 128 + 64 * cg2 + 32 * ct_ + c) << 4));    \
                accv[ct_] = __builtin_amdgcn_mfma_f32_32x32x16_bf16(             \
                                a_, b_, accv[ct_], 0, 0, 0);                     \
            }                                                                    \
        }                                                                        \
    }

    #define FILL_A(slot, kc)                                                     \
    {                                                                            \
        aR[slot][0] = LOAD_A(2 * (kc),     0);                                   \
        aR[slot][1] = LOAD_A(2 * (kc),     1);                                   \
        aR[slot][2] = LOAD_A(2 * (kc) + 1, 0);                                   \
        aR[slot][3] = LOAD_A(2 * (kc) + 1, 1);                                   \
    }

    // ---- GEMM1: hid = relu([src|tgt] @ W_edge + b_edge), K=512, 8 BK=64 chunks
    f32x16 acc[2];
    acc[0] = (f32x16)(0.0f); acc[1] = (f32x16)(0.0f);
    {
        bf16x8 aR[2][4];                     // rolling A buffer, depth 2
        FILL_A(0, 0);                        // prologue: A0, A1, B0, B1
        FILL_A(1, 1);
        STAGE_B64(WTe, 0, 0);
        STAGE_B64(WTe, 1, 1);
        #pragma unroll
        for (int kc = 0; kc < 8; ++kc) {
            int buf = kc & 1;
            // bf16 issue stream: prologue A0(4)A1(4)B0(2)B1(2); per-iter
            // bottom A(kc+2)(4)+B(kc+2)(2). Ledger-derived waits.
            // fp32 fallback: A-loads are compiler-drained at conversion, so
            // counted waits would under-wait on B -> conservative drain.
            if (GBF16) {
                if (kc == 0)      { WAITVL(2); }  // retire A0,A1,B0
                else if (kc < 7)  { WAITVL(6); }  // retire through B(kc)
                else              { WAITVL(0); }  // last chunk: drain
            } else {
                WAITVL(0);
            }
            sbar();                           // SB[buf] visible to all waves
            MFMA_AR64((kc & 1), buf, acc);
            sbar();                           // SB[buf] consumed by all waves
            if (kc < 6) {
                FILL_A((kc & 1), kc + 2);     // just-freed A slot
                STAGE_B64(WTe, kc + 2, buf);  // just-freed B buffer
            }
        }
    }
    // K-GEMM prefetch (flies across the epilogue + lgkm phase barrier)
    STAGE_B64(WTk, 0, 0); STAGE_B64(WTk, 1, 1);
    {   // epilogue: + b_edge, relu -> sHid (bf16, padded fragment order)
        #pragma unroll
        for (int ct = 0; ct < 2; ++ct) {
            int col = 64 * cg2 + 32 * ct + c;
            float bb = sm.sBias[col];
            #pragma unroll
            for (int r = 0; r < 16; ++r) {
                int erow = 32 * rt + (r & 3) + 8 * (r >> 2) + 4 * h5;
                sm.sHid[shid_idx(erow, col)] = f32_to_bf16(fmaxf(acc[ct][r] + bb, 0.f));
            }
        }
    }
    bar_lds();                               // sHid visible; K loads in flight

    // ---- K GEMM: K=128, 2 BK=64 chunks ----
    f32x16 kacc[2];
    kacc[0] = (f32x16)(0.0f); kacc[1] = (f32x16)(0.0f);
    WAITVL(2); sbar();                       // Bk0 landed
    MFMA_H64(0, 0, kacc);
    sbar();
    STAGE_B64(WTv, 0, 0);                    // V prefetch into freed buf0
    WAITVL(2); sbar();                       // Bk1 landed
    MFMA_H64(1, 1, kacc);
    sbar();
    STAGE_B64(WTv, 1, 1);                    // V prefetch into freed buf1

    // ---- scores[e][h] = sum_col Q[rel][col]*(K+bk)[e][col] / sqrt(32) ----
    {
        float ps[2][16];
        #pragma unroll
        for (int ct = 0; ct < 2; ++ct) {
            int col = 64 * cg2 + 32 * ct + c;
            float bk = sm.sBias[HID + col];
            #pragma unroll
            for (int r = 0; r < 16; ++r) {
                int erow = 32 * rt + (r & 3) + 8 * (r >> 2) + 4 * h5;
                ps[ct][r] = (kacc[ct][r] + bk) * sm.sQf[sm.sRel[erow] * HID + col];
            }
        }
        #pragma unroll
        for (int m = 1; m < 32; m <<= 1)
            #pragma unroll
            for (int ct = 0; ct < 2; ++ct)
                #pragma unroll
                for (int r = 0; r < 16; ++r)
                    ps[ct][r] += __shfl_xor(ps[ct][r], m, 64);
        if (c == 0) {
            const float inv = 0.17677669529663687f;   // 1/sqrt(32)
            #pragma unroll
            for (int ct = 0; ct < 2; ++ct) {
                int head = 2 * cg2 + ct;
                #pragma unroll
                for (int r = 0; r < 16; ++r) {
                    int erow = 32 * rt + (r & 3) + 8 * (r >> 2) + 4 * h5;
                    sm.sSc[erow][head] = ps[ct][r] * inv;
                }
            }
        }
    }
    bar_lds();
    if (t < TE) {   // softmax over 4 heads
        float s0 = sm.sSc[t][0], s1 = sm.sSc[t][1];
        float s2 = sm.sSc[t][2], s3 = sm.sSc[t][3];
        float m = fmaxf(fmaxf(s0, s1), fmaxf(s2, s3));
        float e0 = expf(s0 - m), e1 = expf(s1 - m);
        float e2 = expf(s2 - m), e3 = expf(s3 - m);
        float den = e0 + e1 + e2 + e3;
        sm.sAttn[t][0] = e0 / den; sm.sAttn[t][1] = e1 / den;
        sm.sAttn[t][2] = e2 / den; sm.sAttn[t][3] = e3 / den;
    }
    bar_lds();

    // ---- V GEMM: 2 BK=64 chunks ----
    f32x16 vacc[2];
    vacc[0] = (f32x16)(0.0f); vacc[1] = (f32x16)(0.0f);
    WAITVL(2); sbar();                       // Bv0 landed
    MFMA_H64(0, 0, vacc);
    sbar();
    STAGE_B64(WTo1, 0, 0);                   // O prefetch into freed buf0
    WAITVL(2); sbar();                       // Bv1 landed
    MFMA_H64(1, 1, vacc);
    sbar();                                  // all waves' sHid V-reads complete
    STAGE_B64(WTo1, 1, 1);                   // O prefetch into freed buf1

    // ---- attend + residual (in-place on sHid; element-owner = this lane) ----
    {
        #pragma unroll
        for (int ct = 0; ct < 2; ++ct) {
            int col  = 64 * cg2 + 32 * ct + c;
            int head = 2 * cg2 + ct;
            float bv = sm.sBias[2 * HID + col];
            #pragma unroll
            for (int r = 0; r < 16; ++r) {
                int erow = 32 * rt + (r & 3) + 8 * (r >> 2) + 4 * h5;
                float at = sm.sAttn[erow][head];
                int   si = shid_idx(erow, col);
                float hv = bf16_to_f32(sm.sHid[si]);
                sm.sHid[si] = f32_to_bf16(at * (vacc[ct][r] + bv) + hv);
            }
        }
    }
    bar_lds();                               // updated sHid visible

    // ---- GEMM3: 2 BK=64 chunks + final dot with W_o2 ----
    f32x16 oacc[2];
    oacc[0] = (f32x16)(0.0f); oacc[1] = (f32x16)(0.0f);
    WAITVL(2); sbar();                       // Bo0 landed
    MFMA_H64(0, 0, oacc);
    sbar();
    WAITVL(0); sbar();                       // Bo1 landed (nothing follows)
    MFMA_H64(1, 1, oacc);
    sbar();
    {
        float pr[16];
        #pragma unroll
        for (int r = 0; r < 16; ++r) pr[r] = 0.f;
        #pragma unroll
        for (int ct = 0; ct < 2; ++ct) {
            int col = 64 * cg2 + 32 * ct + c;
            float bo = sm.sBias[3 * HID + col];
            float wo = sm.sBias[4 * HID + col];
            #pragma unroll
            for (int r = 0; r < 16; ++r)
                pr[r] += fmaxf(oacc[ct][r] + bo, 0.f) * wo;
        }
        #pragma unroll
        for (int m = 1; m < 32; m <<= 1)
            #pragma unroll
            for (int r = 0; r < 16; ++r)
                pr[r] += __shfl_xor(pr[r], m, 64);
        if (c == 0) {
            #pragma unroll
            for (int r = 0; r < 16; ++r) {
                int erow = 32 * rt + (r & 3) + 8 * (r >> 2) + 4 * h5;
                sm.sPart[erow][cg2] = pr[r];
            }
        }
    }
    bar_lds();
    if (t < TE) {
        int ge = bs + t;
        if (ge < E) {
            float val = sm.sPart[t][0] + sm.sPart[t][1] + ldx<F32>(b_o2, 0);
            // F32 path writes fp32 (round-10 lesson: output buffer is fp32).
            if (F32) ((float*)outp)[ge] = val;
            else     ((unsigned short*)outp)[ge] = f32_to_bf16(val);
        }
    }

    #undef LOAD_A
    #undef STAGE_B64
    #undef MFMA_AR64
    #undef MFMA_H64
    #undef FILL_A
}

__global__ __launch_bounds__(512, 4) void RelationAttentionMLPHead_10539849744626_kernel(
    const void* nodeEmb, const unsigned short* nodeBf16, int useConv,
    const int* edgeIdx, const int* relType,
    const unsigned short* WTe, const unsigned short* WTk,
    const unsigned short* WTv, const unsigned short* WTo1,
    const void* b_edge, const void* b_k, const void* b_v,
    const void* b_o1, const void* W_o2, const void* b_o2,
    const float* Qtab, void* outp, int E)
{
    __shared__ Smem sm;     // single allocation shared by all instantiations
    if (detect_f32(nodeEmb)) {
        if (useConv)
            fused_body<true, true >(sm, nodeBf16, edgeIdx, relType, WTe, WTk, WTv, WTo1,
                                    b_edge, b_k, b_v, b_o1, W_o2, b_o2, Qtab, outp, E);
        else
            fused_body<true, false>(sm, nodeEmb, edgeIdx, relType, WTe, WTk, WTv, WTo1,
                                    b_edge, b_k, b_v, b_o1, W_o2, b_o2, Qtab, outp, E);
    } else {
        // input already bf16: gather straight from the input table
        fused_body<false, true>(sm, nodeEmb, edgeIdx, relType, WTe, WTk, WTv, WTo1,
                                b_edge, b_k, b_v, b_o1, W_o2, b_o2, Qtab, outp, E);
    }
}

extern "C" void kernel_launch(void* const* d_in, const int* in_sizes, int n_in,
                              void* d_out, int out_size, void* d_ws, size_t ws_size,
                              hipStream_t stream) {
    (void)n_in;

    const void* nodeEmb = d_in[0];
    const int*  edgeIdx = (const int*)d_in[1];
    const int*  relType = (const int*)d_in[2];
    const void* rel_emb = d_in[3];
    const void* W_edge  = d_in[4];
    const void* b_edge  = d_in[5];
    const void* W_q     = d_in[6];
    const void* b_q     = d_in[7];
    const void* W_k     = d_in[8];
    const void* b_k     = d_in[9];
    const void* W_v     = d_in[10];
    const void* b_v     = d_in[11];
    const void* W_o1    = d_in[12];
    const void* b_o1    = d_in[13];
    const void* W_o2    = d_in[14];
    const void* b_o2    = d_in[15];

    int E = out_size;
    if (E <= 0) E = in_sizes ? in_sizes[2] : 0;
    if (E <= 0) E = 500000;

    unsigned long long nodeElems =
        (in_sizes && in_sizes[0] > 0) ? (unsigned long long)in_sizes[0] : 25600000ull;

    // d_ws layout (recomputed every launch; graph-safe)
    char* ws = (char*)d_ws;
    float*          Qtab     = (float*)ws;                      // 5120 B
    unsigned short* WTe      = (unsigned short*)(ws + 8192);    // 131072 B
    unsigned short* WTk      = (unsigned short*)(ws + 139264);  // 32768 B
    unsigned short* WTv      = (unsigned short*)(ws + 172032);  // 32768 B
    unsigned short* WTo1     = (unsigned short*)(ws + 204800);  // 32768 B
    unsigned short* nodeBf16 = (unsigned short*)(ws + 237568);  // nodeElems*2 B

    size_t need = 237568ull + nodeElems * 2ull;
    int useConv = (ws_size >= need) ? 1 : 0;
    int convBlocks = useConv ? (int)((nodeElems + 2047ull) / 2048ull) : 0;

    prep_kernel<<<convBlocks + 449, 256, 0, stream>>>(
        nodeEmb, W_edge, W_k, W_v, W_o1, rel_emb, W_q, b_q,
        WTe, WTk, WTv, WTo1, Qtab, nodeBf16, convBlocks, nodeElems);

    int grid = (E + TE - 1) / TE;
    if (grid < 1) grid = 1;

    RelationAttentionMLPHead_10539849744626_kernel<<<grid, 512, 0, stream>>>(
        nodeEmb, nodeBf16, useConv, edgeIdx, relType, WTe, WTk, WTv, WTo1,
        b_edge, b_k, b_v, b_o1, W_o2, b_o2, Qtab, d_out, E);
}

// Round 14
// 385.359 us; speedup vs baseline: 1.1140x; 1.1140x over previous
//
#include <hip/hip_runtime.h>

#define EMB   256
#define HID   128
#define RELD  64
#define NREL  10
#define TE    128
#define SHSTR 130   // sHid k-group stride in 16B units (+2 pad: conflict-free)

typedef __attribute__((ext_vector_type(8)))  short bf16x8;
typedef __attribute__((ext_vector_type(16))) float f32x16;

__device__ __forceinline__ float bf16_to_f32(unsigned short u) {
    union { unsigned int i; float f; } v;
    v.i = ((unsigned int)u) << 16;
    return v.f;
}

__device__ __forceinline__ unsigned short f32_to_bf16(float x) {
    union { unsigned int i; float f; } v;
    v.f = x;
    unsigned int b = v.i;
    unsigned int rounded = b + 0x7fffu + ((b >> 16) & 1u);   // round-nearest-even
    return (unsigned short)(rounded >> 16);
}

template <bool F32>
__device__ __forceinline__ float ldx(const void* p, size_t i) {
    if (F32) return ((const float*)p)[i];
    return bf16_to_f32(((const unsigned short*)p)[i]);
}

// In-kernel parallel dtype detect (validated: fp32 inputs -> true).
__device__ __forceinline__ bool detect_f32(const void* nodeEmb) {
    const float* f = (const float*)nodeEmb;
    float x = f[(threadIdx.x & 63) * 997];
    bool sane = isfinite(x) && fabsf(x) < 1.0e6f;
    unsigned long long m = __ballot(sane);
    return __popcll(m) >= 48;
}

// Register-free async global->LDS (16B per lane). LDS dest must be the
// wave-uniform base; HW adds lane*16.
__device__ __forceinline__ void gload16(const void* g, void* l) {
    __builtin_amdgcn_global_load_lds(
        (const __attribute__((address_space(1))) unsigned int*)g,
        (__attribute__((address_space(3))) unsigned int*)l, 16, 0, 0);
}

// ---- T4 counted-vmcnt barrier kit -----------------------------------------
#define WAITVL(n) asm volatile("s_waitcnt vmcnt(" #n ") lgkmcnt(0)" ::: "memory")

__device__ __forceinline__ void sbar() {           // raw workgroup barrier,
    __builtin_amdgcn_sched_barrier(0);             // no vmcnt drain
    __builtin_amdgcn_s_barrier();
    __builtin_amdgcn_sched_barrier(0);
}
__device__ __forceinline__ void bar_lds() {        // phase barrier: LDS-visible,
    asm volatile("s_waitcnt lgkmcnt(0)" ::: "memory");  // vmem prefetches survive
    sbar();
}

// ---------------------------------------------------------------------------
// Prep kernel (449 blocks — node-conversion pass REMOVED, replaced by the
// pregemm kernel below):
//   blocks [0, 448) : weights -> bf16 in MFMA-FRAGMENT ORDER: per K-chunk
//                     (32 k), 512 16-B units, unit g holds
//                     W[kc*32 + (g>>7)*8 .. +7][g&127].
//                     NOTE: WTe chunks 0..7 = W_top (rows 0..255), chunks
//                     8..15 = W_bot (rows 256..511) — fed to pregemm as-is.
//   block  448      : per-relation Q table (10x128 fp32)
// ---------------------------------------------------------------------------
template <bool F32>
__device__ void prep_body(int vb, const void* W_edge, const void* W_k,
                          const void* W_v, const void* W_o1, const void* rel_emb,
                          const void* W_q, const void* b_q,
                          unsigned short* WTe, unsigned short* WTk,
                          unsigned short* WTv, unsigned short* WTo1, float* Qtab)
{
    if (vb < 448) {
        int idx = vb * 256 + threadIdx.x;             // 0 .. 114687
        if (idx < 65536) {                            // W_edge: 16 chunks x 4096
            int kc = idx >> 12, e = idx & 4095;
            int g = e >> 3, j = e & 7;
            int col = g & 127, kg = g >> 7;
            int k = kc * 32 + kg * 8 + j;
            WTe[idx] = f32_to_bf16(ldx<F32>(W_edge, (size_t)k * HID + col));
        } else if (idx < 65536 + 16384) {             // W_k: 4 chunks x 4096
            int i = idx - 65536;
            int kc = i >> 12, e = i & 4095;
            int g = e >> 3, j = e & 7;
            int col = g & 127, kg = (g >> 7) & 3;
            int k = kc * 32 + kg * 8 + j;
            WTk[i] = f32_to_bf16(ldx<F32>(W_k, (size_t)k * HID + col));
        } else if (idx < 65536 + 2 * 16384) {
            int i = idx - 65536 - 16384;
            int kc = i >> 12, e = i & 4095;
            int g = e >> 3, j = e & 7;
            int col = g & 127, kg = (g >> 7) & 3;
            int k = kc * 32 + kg * 8 + j;
            WTv[i] = f32_to_bf16(ldx<F32>(W_v, (size_t)k * HID + col));
        } else {
            int i = idx - 65536 - 2 * 16384;
            int kc = i >> 12, e = i & 4095;
            int g = e >> 3, j = e & 7;
            int col = g & 127, kg = (g >> 7) & 3;
            int k = kc * 32 + kg * 8 + j;
            WTo1[i] = f32_to_bf16(ldx<F32>(W_o1, (size_t)k * HID + col));
        }
    } else {
        const int t = threadIdx.x;
        const int c = t & (HID - 1);
        const int h = t >> 7;
        for (int r = h; r < NREL; r += 2) {
            float acc = 0.f;
            for (int d = 0; d < RELD; ++d)
                acc += ldx<F32>(rel_emb, r * RELD + d) * ldx<F32>(W_q, (size_t)d * HID + c);
            Qtab[r * HID + c] = acc + ldx<F32>(b_q, c);
        }
    }
}

__global__ void prep_kernel(const void* nodeEmb,
                            const void* W_edge, const void* W_k, const void* W_v,
                            const void* W_o1, const void* rel_emb, const void* W_q,
                            const void* b_q,
                            unsigned short* WTe, unsigned short* WTk,
                            unsigned short* WTv, unsigned short* WTo1, float* Qtab)
{
    bool f32 = detect_f32(nodeEmb);
    if (f32) prep_body<true >(blockIdx.x, W_edge, W_k, W_v, W_o1, rel_emb, W_q, b_q,
                              WTe, WTk, WTv, WTo1, Qtab);
    else     prep_body<false>(blockIdx.x, W_edge, W_k, W_v, W_o1, rel_emb, W_q, b_q,
                              WTe, WTk, WTv, WTo1, Qtab);
}

// ---------------------------------------------------------------------------
// pregemm: per-NODE products HS = nodeEmb @ W_top, HT = nodeEmb @ W_bot
// (bf16 rows, row-major 128 cols). Dense streaming GEMM M=nodeRows, N=128,
// K=256, done once; turns the per-edge 512-B row gather into a 256-B one and
// deletes GEMM1 from the edge kernel. R2-proven staging (syncthreads dbuf).
// ---------------------------------------------------------------------------
struct __align__(16) PSmem {
    unsigned short SA[2][4096];      // 16384 B: A chunk (128 rows x 32 k)
    unsigned short SB[2][2][4096];   // 32768 B: [buf][top/bot] B chunk
};

template <bool F32>
__device__ void pregemm_body(PSmem& ps, const void* nodeEmb,
                             const unsigned short* WTe,
                             unsigned short* HS, unsigned short* HT,
                             long long nodeRows)
{
    const int t   = threadIdx.x;
    const int l   = t & 63;
    const int w   = t >> 6;
    const int c   = l & 31;
    const int h5  = l >> 5;
    const int rt  = w >> 1;
    const int cg2 = w & 1;
    const long long base = (long long)blockIdx.x * 128;

    // staging role: unit t = (s, h5, row)
    const int stRow = t & 127;
    long long arow = base + stRow;
    if (arow >= nodeRows) arow = nodeRows - 1;
    const int colSub = (t >> 8) * 16 + ((t >> 7) & 1) * 8;
    char* const ldsA0 = (char*)ps.SA[0] + w * 1024;
    char* const ldsA1 = (char*)ps.SA[1] + w * 1024;

    #define PSTAGE_A(kc, buf)                                                    \
    {                                                                            \
        size_t eoff = (size_t)arow * EMB + (size_t)((kc) * 32 + colSub);         \
        if (!F32) {                                                              \
            gload16((const unsigned short*)nodeEmb + eoff,                       \
                    (buf) ? ldsA1 : ldsA0);                                      \
        } else {                                                                 \
            const float* p_ = (const float*)nodeEmb + eoff;                      \
            float4 f0_ = *(const float4*)p_;                                     \
            float4 f1_ = *(const float4*)(p_ + 4);                               \
            union { unsigned short us[8]; uint4 v; } pk_;                        \
            pk_.us[0] = f32_to_bf16(f0_.x); pk_.us[1] = f32_to_bf16(f0_.y);      \
            pk_.us[2] = f32_to_bf16(f0_.z); pk_.us[3] = f32_to_bf16(f0_.w);      \
            pk_.us[4] = f32_to_bf16(f1_.x); pk_.us[5] = f32_to_bf16(f1_.y);      \
            pk_.us[6] = f32_to_bf16(f1_.z); pk_.us[7] = f32_to_bf16(f1_.w);      \
            *(uint4*)((char*)ps.SA[(buf)] + t * 16) = pk_.v;                     \
        }                                                                        \
    }
    #define PSTAGE_B(kc, buf)                                                    \
    {                                                                            \
        gload16(WTe + (kc) * 4096 + t * 8,       (char*)ps.SB[(buf)][0] + w * 1024); \
        gload16(WTe + (8 + (kc)) * 4096 + t * 8, (char*)ps.SB[(buf)][1] + w * 1024); \
    }

    f32x16 accP[2], accQ[2];
    accP[0] = (f32x16)(0.0f); accP[1] = (f32x16)(0.0f);
    accQ[0] = (f32x16)(0.0f); accQ[1] = (f32x16)(0.0f);

    PSTAGE_A(0, 0); PSTAGE_B(0, 0);
    __syncthreads();
    #pragma unroll
    for (int kc = 0; kc < 8; ++kc) {
        int buf = kc & 1;
        if (kc < 7) { PSTAGE_A(kc + 1, buf ^ 1); PSTAGE_B(kc + 1, buf ^ 1); }
        const char* sa_ = (const char*)ps.SA[buf];
        #pragma unroll
        for (int s_ = 0; s_ < 2; ++s_) {
            bf16x8 a_ = *(const bf16x8*)(sa_ + ((s_ * 256 + h5 * 128 + 32 * rt + c) << 4));
            #pragma unroll
            for (int ct_ = 0; ct_ < 2; ++ct_) {
                int boff = (s_ * 256 + h5 * 128 + 64 * cg2 + 32 * ct_ + c) << 4;
                bf16x8 bT = *(const bf16x8*)((const char*)ps.SB[buf][0] + boff);
                bf16x8 bB = *(const bf16x8*)((const char*)ps.SB[buf][1] + boff);
                accP[ct_] = __builtin_amdgcn_mfma_f32_32x32x16_bf16(a_, bT, accP[ct_], 0, 0, 0);
                accQ[ct_] = __builtin_amdgcn_mfma_f32_32x32x16_bf16(a_, bB, accQ[ct_], 0, 0, 0);
            }
        }
        __syncthreads();
    }
    // epilogue: row-major bf16 rows (32-lane groups write 64B segments)
    #pragma unroll
    for (int ct = 0; ct < 2; ++ct) {
        int col = 64 * cg2 + 32 * ct + c;
        #pragma unroll
        for (int r = 0; r < 16; ++r) {
            long long grow = base + 32 * rt + (r & 3) + 8 * (r >> 2) + 4 * h5;
            if (grow < nodeRows) {
                HS[grow * HID + col] = f32_to_bf16(accP[ct][r]);
                HT[grow * HID + col] = f32_to_bf16(accQ[ct][r]);
            }
        }
    }
    #undef PSTAGE_A
    #undef PSTAGE_B
}

__global__ __launch_bounds__(512, 2) void pregemm_kernel(
    const void* nodeEmb, const unsigned short* WTe,
    unsigned short* HS, unsigned short* HT, long long nodeRows)
{
    __shared__ PSmem ps;
    if (detect_f32(nodeEmb))
        pregemm_body<true >(ps, nodeEmb, WTe, HS, HT, nodeRows);
    else
        pregemm_body<false>(ps, nodeEmb, WTe, HS, HT, nodeRows);
}

// ---------------------------------------------------------------------------
// Shared memory (both main bodies), 80384 B -> 2 blocks/CU.
// ---------------------------------------------------------------------------
struct __align__(16) Smem {
    unsigned short sHid[16 * SHSTR * 8]; // 33280 B
    unsigned short SB[2][8192];          // 32768 B: double-buffered BK=64 chunk
    float sQf[NREL * HID];               // 5120 B
    float sBias[5 * HID];                // 2560 B: b_edge|b_k|b_v|b_o1|W_o2
    float sSc[TE][4];                    // 2048 B
    float sAttn[TE][4];                  // 2048 B
    float sPart[TE][2];                  // 1024 B
    int   sSrc[TE], sTgt[TE], sRel[TE];  // 1536 B
};

__device__ __forceinline__ int shid_idx(int row, int k) {
    return (((k >> 3) * SHSTR + row) << 3) + (k & 7);
}

template <bool GBF16>
__device__ __forceinline__ bf16x8 loadA8(const void* row, int off) {
    if (GBF16) {
        return *(const bf16x8*)((const unsigned short*)row + off);
    } else {
        const float* p = (const float*)row + off;
        float4 f0 = *(const float4*)p;
        float4 f1 = *(const float4*)(p + 4);
        union { unsigned short us[8]; bf16x8 v; } pk;
        pk.us[0] = f32_to_bf16(f0.x); pk.us[1] = f32_to_bf16(f0.y);
        pk.us[2] = f32_to_bf16(f0.z); pk.us[3] = f32_to_bf16(f0.w);
        pk.us[4] = f32_to_bf16(f1.x); pk.us[5] = f32_to_bf16(f1.y);
        pk.us[6] = f32_to_bf16(f1.z); pk.us[7] = f32_to_bf16(f1.w);
        return pk.v;
    }
}

// ===========================================================================
// NEW main body (useP=1): gather HS[src]+HT[tgt] (256 B rows), add+bias+relu
// -> sHid; then K/score/softmax/V/attend/O identical to R12 (proven).
// ===========================================================================
template <bool F32>
__device__ void fused_body_pre(
    Smem& sm,
    const unsigned short* HS, const unsigned short* HT,
    const int* edgeIdx, const int* relType,
    const unsigned short* WTk, const unsigned short* WTv, const unsigned short* WTo1,
    const void* b_edge, const void* b_k, const void* b_v,
    const void* b_o1, const void* W_o2, const void* b_o2,
    const float* Qtab, void* outp, int E)
{
    const int t   = threadIdx.x;
    const int l   = t & 63;
    const int w   = t >> 6;
    const int c   = l & 31;
    const int h5  = l >> 5;
    const int rt  = w >> 1;
    const int cg2 = w & 1;
    const int bs  = blockIdx.x * TE;
    const int aRow = 32 * rt + c;

    // ---- preamble ----
    if (t < TE) {
        int e = bs + t;
        if (e >= E) e = E - 1;
        if (e < 0)  e = 0;
        sm.sSrc[t] = edgeIdx[e];
        sm.sTgt[t] = edgeIdx[E + e];
        int r = relType[e];
        if (r < 0) r = 0;
        if (r >= NREL) r = NREL - 1;
        sm.sRel[t] = r;
    }
    for (int i = t; i < 5 * HID; i += 512) {
        int which = i >> 7, j = i & (HID - 1);
        float v = (which == 0) ? ldx<F32>(b_edge, j)
                : (which == 1) ? ldx<F32>(b_k, j)
                : (which == 2) ? ldx<F32>(b_v, j)
                : (which == 3) ? ldx<F32>(b_o1, j)
                               : ldx<F32>(W_o2, j);
        sm.sBias[i] = v;
    }
    for (int i = t; i < NREL * HID; i += 512)
        sm.sQf[i] = Qtab[i];
    __syncthreads();

    char* const ldsB0 = (char*)sm.SB[0] + w * 1024;
    char* const ldsB1 = (char*)sm.SB[1] + w * 1024;

    #define STAGE_B64(WT, kc, buf)                                               \
    {                                                                            \
        gload16((WT) + (2 * (kc)    ) * 4096 + t * 8,                            \
                ((buf) ? ldsB1 : ldsB0));                                        \
        gload16((WT) + (2 * (kc) + 1) * 4096 + t * 8,                            \
                ((buf) ? ldsB1 : ldsB0) + 8192);                                 \
    }
    #define MFMA_H64(kc, buf, accv)                                              \
    {                                                                            \
        const char* sb_ = (const char*)sm.SB[(buf)];                             \
        _Pragma("unroll")                                                        \
        for (int h_ = 0; h_ < 2; ++h_)                                           \
        _Pragma("unroll")                                                        \
        for (int s_ = 0; s_ < 2; ++s_) {                                         \
            bf16x8 a_ = *(const bf16x8*)((const char*)sm.sHid +                  \
                ((((2 * (kc) + h_) * 4 + s_ * 2 + h5) * SHSTR + aRow) << 4));    \
            _Pragma("unroll")                                                    \
            for (int ct_ = 0; ct_ < 2; ++ct_) {                                  \
                bf16x8 b_ = *(const bf16x8*)                                     \
                    (sb_ + h_ * 8192 +                                           \
                     ((s_ * 256 + h5 * 128 + 64 * cg2 + 32 * ct_ + c) << 4));    \
                accv[ct_] = __builtin_amdgcn_mfma_f32_32x32x16_bf16(             \
                                a_, b_, accv[ct_], 0, 0, 0);                     \
            }                                                                    \
        }                                                                        \
    }

    // ---- phase 1: hid = relu(HS[src] + HT[tgt] + b_edge) -> sHid ----------
    {
        const int e  = t >> 2;        // 0..127
        const int ug = t & 3;         // 32-col group
        const unsigned short* Pr = HS + (size_t)sm.sSrc[e] * HID + ug * 32;
        const unsigned short* Qr = HT + (size_t)sm.sTgt[e] * HID + ug * 32;
        bf16x8 p0 = *(const bf16x8*)(Pr);      bf16x8 q0 = *(const bf16x8*)(Qr);
        bf16x8 p1 = *(const bf16x8*)(Pr + 8);  bf16x8 q1 = *(const bf16x8*)(Qr + 8);
        bf16x8 p2 = *(const bf16x8*)(Pr + 16); bf16x8 q2 = *(const bf16x8*)(Qr + 16);
        bf16x8 p3 = *(const bf16x8*)(Pr + 24); bf16x8 q3 = *(const bf16x8*)(Qr + 24);
        // K-GEMM prefetch: issued AFTER the gathers -> compiler's data-wait
        // for p/q leaves these 4 gloads in flight (in-order vmcnt).
        STAGE_B64(WTk, 0, 0);
        STAGE_B64(WTk, 1, 1);
        #pragma unroll
        for (int j = 0; j < 4; ++j) {
            bf16x8 pj = (j == 0) ? p0 : (j == 1) ? p1 : (j == 2) ? p2 : p3;
            bf16x8 qj = (j == 0) ? q0 : (j == 1) ? q1 : (j == 2) ? q2 : q3;
            union { unsigned short us[8]; bf16x8 v; } pk;
            #pragma unroll
            for (int i = 0; i < 8; ++i) {
                float f = bf16_to_f32((unsigned short)pj[i])
                        + bf16_to_f32((unsigned short)qj[i])
                        + sm.sBias[ug * 32 + j * 8 + i];
                pk.us[i] = f32_to_bf16(fmaxf(f, 0.f));
            }
            *(bf16x8*)&sm.sHid[(size_t)((ug * 4 + j) * SHSTR + e) * 8] = pk.v;
        }
    }
    bar_lds();                               // sHid visible; Bk loads in flight

    // ---- K GEMM: K=128, 2 BK=64 chunks (verbatim R12) ----
    f32x16 kacc[2];
    kacc[0] = (f32x16)(0.0f); kacc[1] = (f32x16)(0.0f);
    WAITVL(2); sbar();
    MFMA_H64(0, 0, kacc);
    sbar();
    STAGE_B64(WTv, 0, 0);
    WAITVL(2); sbar();
    MFMA_H64(1, 1, kacc);
    sbar();
    STAGE_B64(WTv, 1, 1);

    // ---- scores ----
    {
        float ps[2][16];
        #pragma unroll
        for (int ct = 0; ct < 2; ++ct) {
            int col = 64 * cg2 + 32 * ct + c;
            float bk = sm.sBias[HID + col];
            #pragma unroll
            for (int r = 0; r < 16; ++r) {
                int erow = 32 * rt + (r & 3) + 8 * (r >> 2) + 4 * h5;
                ps[ct][r] = (kacc[ct][r] + bk) * sm.sQf[sm.sRel[erow] * HID + col];
            }
        }
        #pragma unroll
        for (int m = 1; m < 32; m <<= 1)
            #pragma unroll
            for (int ct = 0; ct < 2; ++ct)
                #pragma unroll
                for (int r = 0; r < 16; ++r)
                    ps[ct][r] += __shfl_xor(ps[ct][r], m, 64);
        if (c == 0) {
            const float inv = 0.17677669529663687f;   // 1/sqrt(32)
            #pragma unroll
            for (int ct = 0; ct < 2; ++ct) {
                int head = 2 * cg2 + ct;
                #pragma unroll
                for (int r = 0; r < 16; ++r) {
                    int erow = 32 * rt + (r & 3) + 8 * (r >> 2) + 4 * h5;
                    sm.sSc[erow][head] = ps[ct][r] * inv;
                }
            }
        }
    }
    bar_lds();
    if (t < TE) {   // softmax over 4 heads
        float s0 = sm.sSc[t][0], s1 = sm.sSc[t][1];
        float s2 = sm.sSc[t][2], s3 = sm.sSc[t][3];
        float m = fmaxf(fmaxf(s0, s1), fmaxf(s2, s3));
        float e0 = expf(s0 - m), e1 = expf(s1 - m);
        float e2 = expf(s2 - m), e3 = expf(s3 - m);
        float den = e0 + e1 + e2 + e3;
        sm.sAttn[t][0] = e0 / den; sm.sAttn[t][1] = e1 / den;
        sm.sAttn[t][2] = e2 / den; sm.sAttn[t][3] = e3 / den;
    }
    bar_lds();

    // ---- V GEMM ----
    f32x16 vacc[2];
    vacc[0] = (f32x16)(0.0f); vacc[1] = (f32x16)(0.0f);
    WAITVL(2); sbar();
    MFMA_H64(0, 0, vacc);
    sbar();
    STAGE_B64(WTo1, 0, 0);
    WAITVL(2); sbar();
    MFMA_H64(1, 1, vacc);
    sbar();
    STAGE_B64(WTo1, 1, 1);

    // ---- attend + residual ----
    {
        #pragma unroll
        for (int ct = 0; ct < 2; ++ct) {
            int col  = 64 * cg2 + 32 * ct + c;
            int head = 2 * cg2 + ct;
            float bv = sm.sBias[2 * HID + col];
            #pragma unroll
            for (int r = 0; r < 16; ++r) {
                int erow = 32 * rt + (r & 3) + 8 * (r >> 2) + 4 * h5;
                float at = sm.sAttn[erow][head];
                int   si = shid_idx(erow, col);
                float hv = bf16_to_f32(sm.sHid[si]);
                sm.sHid[si] = f32_to_bf16(at * (vacc[ct][r] + bv) + hv);
            }
        }
    }
    bar_lds();

    // ---- GEMM3 + final dot ----
    f32x16 oacc[2];
    oacc[0] = (f32x16)(0.0f); oacc[1] = (f32x16)(0.0f);
    WAITVL(2); sbar();
    MFMA_H64(0, 0, oacc);
    sbar();
    WAITVL(0); sbar();
    MFMA_H64(1, 1, oacc);
    sbar();
    {
        float pr[16];
        #pragma unroll
        for (int r = 0; r < 16; ++r) pr[r] = 0.f;
        #pragma unroll
        for (int ct = 0; ct < 2; ++ct) {
            int col = 64 * cg2 + 32 * ct + c;
            float bo = sm.sBias[3 * HID + col];
            float wo = sm.sBias[4 * HID + col];
            #pragma unroll
            for (int r = 0; r < 16; ++r)
                pr[r] += fmaxf(oacc[ct][r] + bo, 0.f) * wo;
        }
        #pragma unroll
        for (int m = 1; m < 32; m <<= 1)
            #pragma unroll
            for (int r = 0; r < 16; ++r)
                pr[r] += __shfl_xor(pr[r], m, 64);
        if (c == 0) {
            #pragma unroll
            for (int r = 0; r < 16; ++r) {
                int erow = 32 * rt + (r & 3) + 8 * (r >> 2) + 4 * h5;
                sm.sPart[erow][cg2] = pr[r];
            }
        }
    }
    bar_lds();
    if (t < TE) {
        int ge = bs + t;
        if (ge < E) {
            float val = sm.sPart[t][0] + sm.sPart[t][1] + ldx<F32>(b_o2, 0);
            if (F32) ((float*)outp)[ge] = val;
            else     ((unsigned short*)outp)[ge] = f32_to_bf16(val);
        }
    }
    #undef STAGE_B64
    #undef MFMA_H64
}

// ===========================================================================
// LEGACY body (useP=0 fallback, R12 verbatim): raw node-table gather GEMM1.
// ===========================================================================
template <bool F32, bool GBF16>
__device__ void fused_body(
    Smem& sm,
    const void* gsrc, const int* edgeIdx, const int* relType,
    const unsigned short* WTe, const unsigned short* WTk,
    const unsigned short* WTv, const unsigned short* WTo1,
    const void* b_edge, const void* b_k, const void* b_v,
    const void* b_o1, const void* W_o2, const void* b_o2,
    const float* Qtab, void* outp, int E)
{
    const int t   = threadIdx.x;
    const int l   = t & 63;
    const int w   = t >> 6;
    const int c   = l & 31;
    const int h5  = l >> 5;
    const int rt  = w >> 1;
    const int cg2 = w & 1;
    const int bs  = blockIdx.x * TE;
    const int aRow = 32 * rt + c;

    if (t < TE) {
        int e = bs + t;
        if (e >= E) e = E - 1;
        if (e < 0)  e = 0;
        sm.sSrc[t] = edgeIdx[e];
        sm.sTgt[t] = edgeIdx[E + e];
        int r = relType[e];
        if (r < 0) r = 0;
        if (r >= NREL) r = NREL - 1;
        sm.sRel[t] = r;
    }
    for (int i = t; i < 5 * HID; i += 512) {
        int which = i >> 7, j = i & (HID - 1);
        float v = (which == 0) ? ldx<F32>(b_edge, j)
                : (which == 1) ? ldx<F32>(b_k, j)
                : (which == 2) ? ldx<F32>(b_v, j)
                : (which == 3) ? ldx<F32>(b_o1, j)
                               : ldx<F32>(W_o2, j);
        sm.sBias[i] = v;
    }
    for (int i = t; i < NREL * HID; i += 512)
        sm.sQf[i] = Qtab[i];
    __syncthreads();

    const void* rowSrc;
    const void* rowTgt;
    if (GBF16) {
        rowSrc = (const void*)((const unsigned short*)gsrc + (size_t)sm.sSrc[aRow] * EMB);
        rowTgt = (const void*)((const unsigned short*)gsrc + (size_t)sm.sTgt[aRow] * EMB);
    } else {
        rowSrc = (const void*)((const float*)gsrc + (size_t)sm.sSrc[aRow] * EMB);
        rowTgt = (const void*)((const float*)gsrc + (size_t)sm.sTgt[aRow] * EMB);
    }

    char* const ldsB0 = (char*)sm.SB[0] + w * 1024;
    char* const ldsB1 = (char*)sm.SB[1] + w * 1024;

    #define LOAD_A(k32, s) \
        loadA8<GBF16>(((k32) < 8) ? rowSrc : rowTgt, ((k32) & 7) * 32 + (s) * 16 + h5 * 8)
    #define STAGE_B64(WT, kc, buf)                                               \
    {                                                                            \
        gload16((WT) + (2 * (kc)    ) * 4096 + t * 8,                            \
                ((buf) ? ldsB1 : ldsB0));                                        \
        gload16((WT) + (2 * (kc) + 1) * 4096 + t * 8,                            \
                ((buf) ? ldsB1 : ldsB0) + 8192);                                 \
    }
    #define MFMA_AR64(slot, buf, accv)                                           \
    {                                                                            \
        const char* sb_ = (const char*)sm.SB[(buf)];                             \
        _Pragma("unroll")                                                        \
        for (int h_ = 0; h_ < 2; ++h_)                                           \
        _Pragma("unroll")                                                        \
        for (int s_ = 0; s_ < 2; ++s_) {                                         \
            _Pragma("unroll")                                                    \
            for (int ct_ = 0; ct_ < 2; ++ct_) {                                  \
                bf16x8 b_ = *(const bf16x8*)                                     \
                    (sb_ + h_ * 8192 +                                           \
                     ((s_ * 256 + h5 * 128 + 64 * cg2 + 32 * ct_ + c) << 4));    \
                accv[ct_] = __builtin_amdgcn_mfma_f32_32x32x16_bf16(             \
                                aR[slot][h_ * 2 + s_], b_, accv[ct_], 0, 0, 0);  \
            }                                                                    \
        }                                                                        \
    }
    #define MFMA_H64(kc, buf, accv)                                              \
    {                                                                            \
        const char* sb_ = (const char*)sm.SB[(buf)];                             \
        _Pragma("unroll")                                                        \
        for (int h_ = 0; h_ < 2; ++h_)                                           \
        _Pragma("unroll")                                                        \
        for (int s_ = 0; s_ < 2; ++s_) {                                         \
            bf16x8 a_ = *(const bf16x8*)((const char*)sm.sHid +                  \
                ((((2 * (kc) + h_) * 4 + s_ * 2 + h5) * SHSTR + aRow) << 4));    \
            _Pragma("unroll")                                                    \
            for (int ct_ = 0; ct_ < 2; ++ct_) {                                  \
                bf16x8 b_ = *(const bf16x8*)                                     \
                    (sb_ + h_ * 8192 +                                           \
                     ((s_ * 256 + h5 * 128 + 64 * cg2 + 32 * ct_ + c) << 4));    \
                accv[ct_] = __builtin_amdgcn_mfma_f32_32x32x16_bf16(             \
                                a_, b_, accv[ct_], 0, 0, 0);                     \
            }                                                                    \
        }                                                                        \
    }
    #define FILL_A(slot, kc)                                                     \
    {                                                                            \
        aR[slot][0] = LOAD_A(2 * (kc),     0);                                   \
        aR[slot][1] = LOAD_A(2 * (kc),     1);                                   \
        aR[slot][2] = LOAD_A(2 * (kc) + 1, 0);                                   \
        aR[slot][3] = LOAD_A(2 * (kc) + 1, 1);                                   \
    }

    f32x16 acc[2];
    acc[0] = (f32x16)(0.0f); acc[1] = (f32x16)(0.0f);
    {
        bf16x8 aR[2][4];
        FILL_A(0, 0);
        FILL_A(1, 1);
        STAGE_B64(WTe, 0, 0);
        STAGE_B64(WTe, 1, 1);
        #pragma unroll
        for (int kc = 0; kc < 8; ++kc) {
            int buf = kc & 1;
            if (GBF16) {
                if (kc == 0)      { WAITVL(2); }
                else if (kc < 7)  { WAITVL(6); }
                else              { WAITVL(0); }
            } else {
                WAITVL(0);
            }
            sbar();
            MFMA_AR64((kc & 1), buf, acc);
            sbar();
            if (kc < 6) {
                FILL_A((kc & 1), kc + 2);
                STAGE_B64(WTe, kc + 2, buf);
            }
        }
    }
    STAGE_B64(WTk, 0, 0); STAGE_B64(WTk, 1, 1);
    {
        #pragma unroll
        for (int ct = 0; ct < 2; ++ct) {
            int col = 64 * cg2 + 32 * ct + c;
            float bb = sm.sBias[col];
            #pragma unroll
            for (int r = 0; r < 16; ++r) {
                int erow = 32 * rt + (r & 3) + 8 * (r >> 2) + 4 * h5;
                sm.sHid[shid_idx(erow, col)] = f32_to_bf16(fmaxf(acc[ct][r] + bb, 0.f));
            }
        }
    }
    bar_lds();

    f32x16 kacc[2];
    kacc[0] = (f32x16)(0.0f); kacc[1] = (f32x16)(0.0f);
    WAITVL(2); sbar();
    MFMA_H64(0, 0, kacc);
    sbar();
    STAGE_B64(WTv, 0, 0);
    WAITVL(2); sbar();
    MFMA_H64(1, 1, kacc);
    sbar();
    STAGE_B64(WTv, 1, 1);

    {
        float ps[2][16];
        #pragma unroll
        for (int ct = 0; ct < 2; ++ct) {
            int col = 64 * cg2 + 32 * ct + c;
            float bk = sm.sBias[HID + col];
            #pragma unroll
            for (int r = 0; r < 16; ++r) {
                int erow = 32 * rt + (r & 3) + 8 * (r >> 2) + 4 * h5;
                ps[ct][r] = (kacc[ct][r] + bk) * sm.sQf[sm.sRel[erow] * HID + col];
            }
        }
        #pragma unroll
        for (int m = 1; m < 32; m <<= 1)
            #pragma unroll
            for (int ct = 0; ct < 2; ++ct)
                #pragma unroll
                for (int r = 0; r < 16; ++r)
                    ps[ct][r] += __shfl_xor(ps[ct][r], m, 64);
        if (c == 0) {
            const float inv = 0.17677669529663687f;
            #pragma unroll
            for (int ct = 0; ct < 2; ++ct) {
                int head = 2 * cg2 + ct;
                #pragma unroll
                for (int r = 0; r < 16; ++r) {
                    int erow = 32 * rt + (r & 3) + 8 * (r >> 2) + 4 * h5;
                    sm.sSc[erow][head] = ps[ct][r] * inv;
                }
            }
        }
    }
    bar_lds();
    if (t < TE) {
        float s0 = sm.sSc[t][0], s1 = sm.sSc[t][1];
        float s2 = sm.sSc[t][2], s3 = sm.sSc[t][3];
        float m = fmaxf(fmaxf(s0, s1), fmaxf(s2, s3));
        float e0 = expf(s0 - m), e1 = expf(s1 - m);
        float e2 = expf(s2 - m), e3 = expf(s3 - m);
        float den = e0 + e1 + e2 + e3;
        sm.sAttn[t][0] = e0 / den; sm.sAttn[t][1] = e1 / den;
        sm.sAttn[t][2] = e2 / den; sm.sAttn[t][3] = e3 / den;
    }
    bar_lds();

    f32x16 vacc[2];
    vacc[0] = (f32x16)(0.0f); vacc[1] = (f32x16)(0.0f);
    WAITVL(2); sbar();
    MFMA_H64(0, 0, vacc);
    sbar();
    STAGE_B64(WTo1, 0, 0);
    WAITVL(2); sbar();
    MFMA_H64(1, 1, vacc);
    sbar();
    STAGE_B64(WTo1, 1, 1);

    {
        #pragma unroll
        for (int ct = 0; ct < 2; ++ct) {
            int col  = 64 * cg2 + 32 * ct + c;
            int head = 2 * cg2 + ct;
            float bv = sm.sBias[2 * HID + col];
            #pragma unroll
            for (int r = 0; r < 16; ++r) {
                int erow = 32 * rt + (r & 3) + 8 * (r >> 2) + 4 * h5;
                float at = sm.sAttn[erow][head];
                int   si = shid_idx(erow, col);
                float hv = bf16_to_f32(sm.sHid[si]);
                sm.sHid[si] = f32_to_bf16(at * (vacc[ct][r] + bv) + hv);
            }
        }
    }
    bar_lds();

    f32x16 oacc[2];
    oacc[0] = (f32x16)(0.0f); oacc[1] = (f32x16)(0.0f);
    WAITVL(2); sbar();
    MFMA_H64(0, 0, oacc);
    sbar();
    WAITVL(0); sbar();
    MFMA_H64(1, 1, oacc);
    sbar();
    {
        float pr[16];
        #pragma unroll
        for (int r = 0; r < 16; ++r) pr[r] = 0.f;
        #pragma unroll
        for (int ct = 0; ct < 2; ++ct) {
            int col = 64 * cg2 + 32 * ct + c;
            float bo = sm.sBias[3 * HID + col];
            float wo = sm.sBias[4 * HID + col];
            #pragma unroll
            for (int r = 0; r < 16; ++r)
                pr[r] += fmaxf(oacc[ct][r] + bo, 0.f) * wo;
        }
        #pragma unroll
        for (int m = 1; m < 32; m <<= 1)
            #pragma unroll
            for (int r = 0; r < 16; ++r)
                pr[r] += __shfl_xor(pr[r], m, 64);
        if (c == 0) {
            #pragma unroll
            for (int r = 0; r < 16; ++r) {
                int erow = 32 * rt + (r & 3) + 8 * (r >> 2) + 4 * h5;
                sm.sPart[erow][cg2] = pr[r];
            }
        }
    }
    bar_lds();
    if (t < TE) {
        int ge = bs + t;
        if (ge < E) {
            float val = sm.sPart[t][0] + sm.sPart[t][1] + ldx<F32>(b_o2, 0);
            if (F32) ((float*)outp)[ge] = val;
            else     ((unsigned short*)outp)[ge] = f32_to_bf16(val);
        }
    }
    #undef LOAD_A
    #undef STAGE_B64
    #undef MFMA_AR64
    #undef MFMA_H64
    #undef FILL_A
}

__global__ __launch_bounds__(512, 4) void RelationAttentionMLPHead_10539849744626_kernel(
    const void* nodeEmb, const unsigned short* HS, const unsigned short* HT, int useP,
    const int* edgeIdx, const int* relType,
    const unsigned short* WTe, const unsigned short* WTk,
    const unsigned short* WTv, const unsigned short* WTo1,
    const void* b_edge, const void* b_k, const void* b_v,
    const void* b_o1, const void* W_o2, const void* b_o2,
    const float* Qtab, void* outp, int E)
{
    __shared__ Smem sm;
    bool f32 = detect_f32(nodeEmb);
    if (useP) {
        if (f32) fused_body_pre<true >(sm, HS, HT, edgeIdx, relType, WTk, WTv, WTo1,
                                       b_edge, b_k, b_v, b_o1, W_o2, b_o2, Qtab, outp, E);
        else     fused_body_pre<false>(sm, HS, HT, edgeIdx, relType, WTk, WTv, WTo1,
                                       b_edge, b_k, b_v, b_o1, W_o2, b_o2, Qtab, outp, E);
    } else {
        if (f32) fused_body<true, false>(sm, nodeEmb, edgeIdx, relType, WTe, WTk, WTv, WTo1,
                                         b_edge, b_k, b_v, b_o1, W_o2, b_o2, Qtab, outp, E);
        else     fused_body<false, true>(sm, nodeEmb, edgeIdx, relType, WTe, WTk, WTv, WTo1,
                                         b_edge, b_k, b_v, b_o1, W_o2, b_o2, Qtab, outp, E);
    }
}

extern "C" void kernel_launch(void* const* d_in, const int* in_sizes, int n_in,
                              void* d_out, int out_size, void* d_ws, size_t ws_size,
                              hipStream_t stream) {
    (void)n_in;

    const void* nodeEmb = d_in[0];
    const int*  edgeIdx = (const int*)d_in[1];
    const int*  relType = (const int*)d_in[2];
    const void* rel_emb = d_in[3];
    const void* W_edge  = d_in[4];
    const void* b_edge  = d_in[5];
    const void* W_q     = d_in[6];
    const void* b_q     = d_in[7];
    const void* W_k     = d_in[8];
    const void* b_k     = d_in[9];
    const void* W_v     = d_in[10];
    const void* b_v     = d_in[11];
    const void* W_o1    = d_in[12];
    const void* b_o1    = d_in[13];
    const void* W_o2    = d_in[14];
    const void* b_o2    = d_in[15];

    int E = out_size;
    if (E <= 0) E = in_sizes ? in_sizes[2] : 0;
    if (E <= 0) E = 500000;

    unsigned long long nodeElems =
        (in_sizes && in_sizes[0] > 0) ? (unsigned long long)in_sizes[0] : 25600000ull;
    long long nodeRows = (long long)(nodeElems / EMB);
    if (nodeRows < 1) nodeRows = 1;

    // d_ws layout (recomputed every launch; graph-safe)
    char* ws = (char*)d_ws;
    float*          Qtab = (float*)ws;                      // 5120 B (8192 rsvd)
    unsigned short* WTe  = (unsigned short*)(ws + 8192);    // 131072 B
    unsigned short* WTk  = (unsigned short*)(ws + 139264);  // 32768 B
    unsigned short* WTv  = (unsigned short*)(ws + 172032);  // 32768 B
    unsigned short* WTo1 = (unsigned short*)(ws + 204800);  // 32768 B
    unsigned short* HS   = (unsigned short*)(ws + 237568);  // nodeRows*256 B
    unsigned short* HT   = HS + (size_t)nodeRows * HID;     // nodeRows*256 B

    size_t need = 237568ull + (size_t)nodeRows * 512ull;
    int useP = (ws_size >= need) ? 1 : 0;

    prep_kernel<<<449, 256, 0, stream>>>(
        nodeEmb, W_edge, W_k, W_v, W_o1, rel_emb, W_q, b_q,
        WTe, WTk, WTv, WTo1, Qtab);

    if (useP) {
        int pgrid = (int)((nodeRows + 127) / 128);
        pregemm_kernel<<<pgrid, 512, 0, stream>>>(nodeEmb, WTe, HS, HT, nodeRows);
    }

    int grid = (E + TE - 1) / TE;
    if (grid < 1) grid = 1;

    RelationAttentionMLPHead_10539849744626_kernel<<<grid, 512, 0, stream>>>(
        nodeEmb, HS, HT, useP, edgeIdx, relType, WTe, WTk, WTv, WTo1,
        b_edge, b_k, b_v, b_o1, W_o2, b_o2, Qtab, d_out, E);
}